// Round 1
// baseline (484.753 us; speedup 1.0000x reference)
//
#include <hip/hip_runtime.h>
#include <hip/hip_bf16.h>

#define N_TOK   16384   // B * N_PEP
#define NREC    10
#define EMB     256
#define TWO_EMB 512
#define OUTD    256
#define T_BLK   8       // tokens per block
#define M_ROWS  80      // T_BLK * NREC
#define THREADS 512

typedef __bf16 bf16x8 __attribute__((ext_vector_type(8)));
typedef float  f32x4  __attribute__((ext_vector_type(4)));

static __device__ __forceinline__ unsigned int f2bf_bits(float f) {
    unsigned int u = __builtin_bit_cast(unsigned int, f);
    // round-to-nearest-even bf16 truncation (inputs are finite)
    u = (u + 0x7fffu + ((u >> 16) & 1u)) >> 16;
    return u & 0xffffu;
}

static __device__ __forceinline__ int lds_addr(int row, int kbyte) {
    // 512-byte rows ([256] bf16); XOR swizzle spreads the column stripe over 8 banks-groups
    return row * 512 + (kbyte ^ ((row & 7) << 4));
}

// ---------------- weight fragment prep (runs every call; ~1.3 MB of writes) ----
__global__ void prep_wfrag(const float* __restrict__ Wp,
                           const float* __restrict__ Wr,
                           const float* __restrict__ Wv,
                           short* __restrict__ wp_frag,   // [16 nt][8 kt][64][8]
                           short* __restrict__ w_frag) {  // [32 nt][16 kt][64][8]
    int idx = blockIdx.x * blockDim.x + threadIdx.x;
    if (idx < 32 * 16 * 64 * 8) {
        int j = idx & 7, lane = (idx >> 3) & 63, kt = (idx >> 9) & 15, nt = idx >> 13;
        int n = nt * 16 + (lane & 15);
        int k = kt * 32 + ((lane >> 4) << 3) + j;
        float v = (n < 256) ? Wr[n * TWO_EMB + k] : Wv[(n - 256) * TWO_EMB + k];
        w_frag[idx] = (short)f2bf_bits(v);
    }
    if (idx < 16 * 8 * 64 * 8) {
        int j = idx & 7, lane = (idx >> 3) & 63, kt = (idx >> 9) & 7, nt = idx >> 12;
        int n = nt * 16 + (lane & 15);
        int k = kt * 32 + ((lane >> 4) << 3) + j;
        wp_frag[idx] = (short)f2bf_bits(Wp[n * EMB + k]);
    }
}

// ---------------- fused graph-attention kernel --------------------------------
__launch_bounds__(THREADS, 2)
__global__ void ga_fused(const float* __restrict__ rec,
                         const float* __restrict__ pep,
                         const float* __restrict__ edge,
                         const float* __restrict__ Wp_w,
                         const float* __restrict__ Wp_b,
                         const float* __restrict__ Wr_w,
                         const float* __restrict__ Wv_w,
                         const float* __restrict__ Wv_b,
                         const short* __restrict__ w_frag,
                         const short* __restrict__ wp_frag,
                         int use_frag,
                         float* __restrict__ out) {
    // A-tile: 80 rows x 256 bf16 (one 256-wide K chunk), swizzled. Rows 0..15 alias
    // the pep tile during the Q phase.
    __shared__ __align__(16) unsigned char Abuf[M_ROWS * 512];          // 40 KB
    __shared__ float q_lds[T_BLK][OUTD];                                 // 8 KB
    __shared__ float out_acc[T_BLK][OUTD];                               // 8 KB
    __shared__ float logits[M_ROWS];
    __shared__ float attnw[M_ROWS];

    const int tid  = threadIdx.x;
    const int lane = tid & 63;
    const int wave = tid >> 6;            // 0..7
    const int tok0 = blockIdx.x * T_BLK;
    const long grow0 = (long)tok0 * NREC; // first global (token,r) row

    // ---- init accumul. LDS + stage pep tile (rows 8..15 zero) ----
    for (int i = tid; i < T_BLK * OUTD; i += THREADS) ((float*)out_acc)[i] = 0.f;
    if (tid < M_ROWS) logits[tid] = 0.f;

    #pragma unroll
    for (int it = 0; it < 2; ++it) {
        int idx = tid + it * THREADS;       // 0..1023 : 16 rows x 64 float4
        int row = idx >> 6, d4 = (idx & 63) << 2;
        float4 f;
        if (row < T_BLK) f = *reinterpret_cast<const float4*>(pep + (long)(tok0 + row) * EMB + d4);
        else             f = make_float4(0.f, 0.f, 0.f, 0.f);
        unsigned int w0 = f2bf_bits(f.x) | (f2bf_bits(f.y) << 16);
        unsigned int w1 = f2bf_bits(f.z) | (f2bf_bits(f.w) << 16);
        *reinterpret_cast<uint2*>(Abuf + lds_addr(row, d4 * 2)) = make_uint2(w0, w1);
    }
    __syncthreads();

    // ---- Q GEMM: M=8(pad16) x K=256 x N=256; wave handles 2 n-tiles ----
    {
        f32x4 qacc[2] = {};
        const int arow = lane & 15;
        #pragma unroll
        for (int kt = 0; kt < 8; ++kt) {
            int kk = kt * 32 + ((lane >> 4) << 3);
            bf16x8 a = *reinterpret_cast<const bf16x8*>(Abuf + lds_addr(arow, kk * 2));
            #pragma unroll
            for (int ntl = 0; ntl < 2; ++ntl) {
                int nt = wave * 2 + ntl;
                bf16x8 b;
                if (use_frag) {
                    b = *reinterpret_cast<const bf16x8*>(wp_frag + (((nt * 8 + kt) << 6) + lane) * 8);
                } else {
                    int n = nt * 16 + (lane & 15);
                    const float* src = Wp_w + n * EMB + kk;
                    float4 f0 = *reinterpret_cast<const float4*>(src);
                    float4 f1 = *reinterpret_cast<const float4*>(src + 4);
                    uint4 t;
                    t.x = f2bf_bits(f0.x) | (f2bf_bits(f0.y) << 16);
                    t.y = f2bf_bits(f0.z) | (f2bf_bits(f0.w) << 16);
                    t.z = f2bf_bits(f1.x) | (f2bf_bits(f1.y) << 16);
                    t.w = f2bf_bits(f1.z) | (f2bf_bits(f1.w) << 16);
                    b = __builtin_bit_cast(bf16x8, t);
                }
                qacc[ntl] = __builtin_amdgcn_mfma_f32_16x16x32_bf16(a, b, qacc[ntl], 0, 0, 0);
            }
        }
        #pragma unroll
        for (int ntl = 0; ntl < 2; ++ntl) {
            int n = (wave * 2 + ntl) * 16 + (lane & 15);
            float bias = Wp_b[n];
            #pragma unroll
            for (int i = 0; i < 4; ++i) {
                int row = ((lane >> 4) << 2) + i;
                if (row < T_BLK) q_lds[row][n] = qacc[ntl][i] + bias;
            }
        }
    }
    __syncthreads();   // pep tile dead; q_lds visible

    // ---- K/V GEMM: M=80 x K=512 x N=512 (waves 0-3: K cols, 4-7: V cols) ----
    f32x4 acc[5][4] = {};
    #pragma unroll
    for (int kc = 0; kc < 2; ++kc) {
        const float* srcT = kc ? edge : rec;       // chunk = one source tensor
        #pragma unroll
        for (int it = 0; it < 10; ++it) {
            int idx = tid + it * THREADS;           // 80 rows x 64 float4
            int row = idx >> 6, d4 = (idx & 63) << 2;
            float4 f = *reinterpret_cast<const float4*>(srcT + (grow0 + row) * EMB + d4);
            unsigned int w0 = f2bf_bits(f.x) | (f2bf_bits(f.y) << 16);
            unsigned int w1 = f2bf_bits(f.z) | (f2bf_bits(f.w) << 16);
            *reinterpret_cast<uint2*>(Abuf + lds_addr(row, d4 * 2)) = make_uint2(w0, w1);
        }
        __syncthreads();
        #pragma unroll
        for (int kt = 0; kt < 8; ++kt) {
            int ktg = kc * 8 + kt;
            int kk = kt * 32 + ((lane >> 4) << 3);   // chunk-local k
            bf16x8 a[5];
            #pragma unroll
            for (int mt = 0; mt < 5; ++mt)
                a[mt] = *reinterpret_cast<const bf16x8*>(Abuf + lds_addr(mt * 16 + (lane & 15), kk * 2));
            #pragma unroll
            for (int ntl = 0; ntl < 4; ++ntl) {
                int nt = wave * 4 + ntl;
                bf16x8 b;
                if (use_frag) {
                    b = *reinterpret_cast<const bf16x8*>(w_frag + (((nt * 16 + ktg) << 6) + lane) * 8);
                } else {
                    int n = nt * 16 + (lane & 15);
                    int kkg = ktg * 32 + ((lane >> 4) << 3);
                    const float* src = (n < 256) ? (Wr_w + n * TWO_EMB + kkg)
                                                 : (Wv_w + (n - 256) * TWO_EMB + kkg);
                    float4 f0 = *reinterpret_cast<const float4*>(src);
                    float4 f1 = *reinterpret_cast<const float4*>(src + 4);
                    uint4 t;
                    t.x = f2bf_bits(f0.x) | (f2bf_bits(f0.y) << 16);
                    t.y = f2bf_bits(f0.z) | (f2bf_bits(f0.w) << 16);
                    t.z = f2bf_bits(f1.x) | (f2bf_bits(f1.y) << 16);
                    t.w = f2bf_bits(f1.z) | (f2bf_bits(f1.w) << 16);
                    b = __builtin_bit_cast(bf16x8, t);
                }
                #pragma unroll
                for (int mt = 0; mt < 5; ++mt)
                    acc[mt][ntl] = __builtin_amdgcn_mfma_f32_16x16x32_bf16(a[mt], b, acc[mt][ntl], 0, 0, 0);
            }
        }
        __syncthreads();
    }

    // ---- logits: waves 0-3 reduce q . K straight from acc registers ----
    if (wave < 4) {
        #pragma unroll
        for (int mt = 0; mt < 5; ++mt) {
            #pragma unroll
            for (int i = 0; i < 4; ++i) {
                int row = mt * 16 + ((lane >> 4) << 2) + i;   // 0..79
                int t = row / NREC;
                float p = 0.f;
                #pragma unroll
                for (int ntl = 0; ntl < 4; ++ntl) {
                    int n = wave * 64 + ntl * 16 + (lane & 15);
                    p += acc[mt][ntl][i] * q_lds[t][n];
                }
                p += __shfl_xor(p, 1);
                p += __shfl_xor(p, 2);
                p += __shfl_xor(p, 4);
                p += __shfl_xor(p, 8);
                if ((lane & 15) == 0) atomicAdd(&logits[row], p);
            }
        }
    }
    __syncthreads();

    // ---- softmax over the 10 neighbors (Wr_b dropped: shift-invariant) ----
    if (tid < T_BLK) {
        float l[NREC], m = -1e30f;
        #pragma unroll
        for (int r = 0; r < NREC; ++r) { l[r] = logits[tid * NREC + r] * 0.0625f; m = fmaxf(m, l[r]); }
        float s = 0.f;
        #pragma unroll
        for (int r = 0; r < NREC; ++r) { l[r] = expf(l[r] - m); s += l[r]; }
        float inv = 1.f / s;
        #pragma unroll
        for (int r = 0; r < NREC; ++r) attnw[tid * NREC + r] = l[r] * inv;
    }
    __syncthreads();

    // ---- attention-weighted V accumulation (waves 4-7, from acc registers) ----
    if (wave >= 4) {
        #pragma unroll
        for (int mt = 0; mt < 5; ++mt) {
            #pragma unroll
            for (int i = 0; i < 4; ++i) {
                int row = mt * 16 + ((lane >> 4) << 2) + i;
                int t = row / NREC;
                float w = attnw[row];
                #pragma unroll
                for (int ntl = 0; ntl < 4; ++ntl) {
                    int nv = (wave - 4) * 64 + ntl * 16 + (lane & 15);
                    atomicAdd(&out_acc[t][nv], w * acc[mt][ntl][i]);
                }
            }
        }
    }
    __syncthreads();

    // ---- epilogue: out = q + attn*V + Wv_b  (sum(attn)=1 folds the V bias) ----
    #pragma unroll
    for (int it = 0; it < 4; ++it) {
        int idx = tid + it * THREADS;
        int t = idx >> 8, o = idx & 255;
        out[(long)(tok0 + t) * OUTD + o] = q_lds[t][o] + out_acc[t][o] + Wv_b[o];
    }
}

extern "C" void kernel_launch(void* const* d_in, const int* in_sizes, int n_in,
                              void* d_out, int out_size, void* d_ws, size_t ws_size,
                              hipStream_t stream) {
    const float* rec  = (const float*)d_in[0];
    const float* pep  = (const float*)d_in[1];
    const float* edge = (const float*)d_in[2];
    const float* Wp_w = (const float*)d_in[3];
    const float* Wp_b = (const float*)d_in[4];
    const float* Wr_w = (const float*)d_in[5];
    // d_in[6] = Wr_b : provably irrelevant (softmax shift invariance)
    const float* Wv_w = (const float*)d_in[7];
    const float* Wv_b = (const float*)d_in[8];
    float* out = (float*)d_out;

    const size_t kv_frag_elems = 32 * 16 * 64 * 8;   // 262144
    const size_t qp_frag_elems = 16 * 8 * 64 * 8;    // 65536
    const size_t need = (kv_frag_elems + qp_frag_elems) * sizeof(short);
    int use_frag = (ws_size >= need) ? 1 : 0;
    short* w_frag  = (short*)d_ws;
    short* wp_frag = w_frag + kv_frag_elems;

    if (use_frag) {
        prep_wfrag<<<1024, 256, 0, stream>>>(Wp_w, Wr_w, Wv_w, wp_frag, w_frag);
    }
    ga_fused<<<N_TOK / T_BLK, THREADS, 0, stream>>>(rec, pep, edge, Wp_w, Wp_b, Wr_w,
                                                    Wv_w, Wv_b, w_frag, wp_frag, use_frag, out);
}

// Round 2
// 251.052 us; speedup vs baseline: 1.9309x; 1.9309x over previous
//
#include <hip/hip_runtime.h>
#include <hip/hip_bf16.h>

#define N_TOK   16384   // B * N_PEP
#define NREC    10
#define EMB     256
#define TWO_EMB 512
#define OUTD    256
#define T_BLK   8       // tokens per block
#define M_ROWS  80      // T_BLK * NREC
#define THREADS 512

typedef __bf16 bf16x8 __attribute__((ext_vector_type(8)));
typedef float  f32x4  __attribute__((ext_vector_type(4)));

static __device__ __forceinline__ unsigned int f2bf_bits(float f) {
    unsigned int u = __builtin_bit_cast(unsigned int, f);
    u = (u + 0x7fffu + ((u >> 16) & 1u)) >> 16;   // RNE bf16
    return u & 0xffffu;
}

static __device__ __forceinline__ int lds_addr(int row, int kbyte) {
    // 512-byte rows ([256] bf16); XOR swizzle: 16 rows of a column stripe -> 8 slots (2-way = free)
    return row * 512 + (kbyte ^ ((row & 7) << 4));
}

// ---------------- weight fragment prep (bf16, MFMA B-fragment order) ----------
__global__ void prep_wfrag(const float* __restrict__ Wp,
                           const float* __restrict__ Wr,
                           const float* __restrict__ Wv,
                           short* __restrict__ wp_frag,   // [16 nt][8 kt][64][8]
                           short* __restrict__ w_frag) {  // [32 nt][16 kt][64][8]
    int idx = blockIdx.x * blockDim.x + threadIdx.x;
    if (idx < 32 * 16 * 64 * 8) {
        int j = idx & 7, lane = (idx >> 3) & 63, kt = (idx >> 9) & 15, nt = idx >> 13;
        int n = nt * 16 + (lane & 15);
        int k = kt * 32 + ((lane >> 4) << 3) + j;
        float v = (n < 256) ? Wr[n * TWO_EMB + k] : Wv[(n - 256) * TWO_EMB + k];
        w_frag[idx] = (short)f2bf_bits(v);
    }
    if (idx < 16 * 8 * 64 * 8) {
        int j = idx & 7, lane = (idx >> 3) & 63, kt = (idx >> 9) & 7, nt = idx >> 12;
        int n = nt * 16 + (lane & 15);
        int k = kt * 32 + ((lane >> 4) << 3) + j;
        wp_frag[idx] = (short)f2bf_bits(Wp[n * EMB + k]);
    }
}

// ---- K/V chunk compute: 8 kt steps of K=32; kc selects global K-half ---------
template<int USE_FRAG>
static __device__ __forceinline__ void kv_compute(
    int kc, const unsigned char* Ab, const short* __restrict__ w_frag,
    const float* __restrict__ Wr_w, const float* __restrict__ Wv_w,
    int lane, int wave, f32x4 (&acc)[5][4])
{
    #pragma unroll
    for (int kt = 0; kt < 8; ++kt) {
        int kk = kt * 32 + ((lane >> 4) << 3);     // chunk-local k
        bf16x8 a[5];
        #pragma unroll
        for (int mt = 0; mt < 5; ++mt)
            a[mt] = *reinterpret_cast<const bf16x8*>(Ab + lds_addr(mt * 16 + (lane & 15), kk * 2));
        #pragma unroll
        for (int ntl = 0; ntl < 4; ++ntl) {
            int nt = wave * 4 + ntl;
            int ktg = kc * 8 + kt;
            bf16x8 b;
            if (USE_FRAG) {
                b = *reinterpret_cast<const bf16x8*>(w_frag + (((nt * 16 + ktg) << 6) + lane) * 8);
            } else {
                int n = nt * 16 + (lane & 15);
                int kkg = ktg * 32 + ((lane >> 4) << 3);
                const float* src = (n < 256) ? (Wr_w + n * TWO_EMB + kkg)
                                             : (Wv_w + (n - 256) * TWO_EMB + kkg);
                float4 f0 = *reinterpret_cast<const float4*>(src);
                float4 f1 = *reinterpret_cast<const float4*>(src + 4);
                uint4 t;
                t.x = f2bf_bits(f0.x) | (f2bf_bits(f0.y) << 16);
                t.y = f2bf_bits(f0.z) | (f2bf_bits(f0.w) << 16);
                t.z = f2bf_bits(f1.x) | (f2bf_bits(f1.y) << 16);
                t.w = f2bf_bits(f1.z) | (f2bf_bits(f1.w) << 16);
                b = __builtin_bit_cast(bf16x8, t);
            }
            #pragma unroll
            for (int mt = 0; mt < 5; ++mt)
                acc[mt][ntl] = __builtin_amdgcn_mfma_f32_16x16x32_bf16(a[mt], b, acc[mt][ntl], 0, 0, 0);
        }
    }
}

// ---------------- fused graph-attention kernel --------------------------------
template<int USE_FRAG>
__launch_bounds__(THREADS, 2)
__global__ void ga_fused(const float* __restrict__ rec,
                         const float* __restrict__ pep,
                         const float* __restrict__ edge,
                         const float* __restrict__ Wp_w,
                         const float* __restrict__ Wp_b,
                         const float* __restrict__ Wr_w,
                         const float* __restrict__ Wv_w,
                         const float* __restrict__ Wv_b,
                         const short* __restrict__ w_frag,
                         const short* __restrict__ wp_frag,
                         float* __restrict__ out) {
    __shared__ __align__(16) unsigned char Abuf[M_ROWS * 512];   // 40 KB
    __shared__ float q_lds[T_BLK][OUTD];                          // 8 KB
    __shared__ float out_acc[T_BLK][OUTD];                        // 8 KB
    __shared__ float logit_part[4][M_ROWS];                       // 1.25 KB
    __shared__ float attnw[M_ROWS];

    const int tid  = threadIdx.x;
    const int lane = tid & 63;
    const int wave = tid >> 6;            // 0..7
    const int tok0 = blockIdx.x * T_BLK;
    const long grow0 = (long)tok0 * NREC;

    for (int i = tid; i < T_BLK * OUTD; i += THREADS) ((float*)out_acc)[i] = 0.f;

    // ---- stage pep tile (rows 8..15 zero) ----
    #pragma unroll
    for (int it = 0; it < 2; ++it) {
        int idx = tid + it * THREADS;     // 16 rows x 64 float4
        int row = idx >> 6, d4 = (idx & 63) << 2;
        float4 f;
        if (row < T_BLK) f = *reinterpret_cast<const float4*>(pep + (long)(tok0 + row) * EMB + d4);
        else             f = make_float4(0.f, 0.f, 0.f, 0.f);
        unsigned int w0 = f2bf_bits(f.x) | (f2bf_bits(f.y) << 16);
        unsigned int w1 = f2bf_bits(f.z) | (f2bf_bits(f.w) << 16);
        *reinterpret_cast<uint2*>(Abuf + lds_addr(row, d4 * 2)) = make_uint2(w0, w1);
    }
    __syncthreads();                                   // B1: pep tile ready

    // ---- T14: issue chunk-0 (rec) global loads; they drain during Q GEMM ----
    float4 pf[10];
    #pragma unroll
    for (int it = 0; it < 10; ++it) {
        int idx = tid + it * THREADS;                  // 80 rows x 64 float4
        int row = idx >> 6, d4 = (idx & 63) << 2;
        pf[it] = *reinterpret_cast<const float4*>(rec + (grow0 + row) * EMB + d4);
    }

    // ---- Q GEMM: M=8(pad16) x K=256 x N=256; each wave 2 n-tiles ----
    {
        f32x4 qacc[2] = {};
        const int arow = lane & 15;
        #pragma unroll
        for (int kt = 0; kt < 8; ++kt) {
            int kk = kt * 32 + ((lane >> 4) << 3);
            bf16x8 a = *reinterpret_cast<const bf16x8*>(Abuf + lds_addr(arow, kk * 2));
            #pragma unroll
            for (int ntl = 0; ntl < 2; ++ntl) {
                int nt = wave * 2 + ntl;
                bf16x8 b;
                if (USE_FRAG) {
                    b = *reinterpret_cast<const bf16x8*>(wp_frag + (((nt * 8 + kt) << 6) + lane) * 8);
                } else {
                    int n = nt * 16 + (lane & 15);
                    const float* src = Wp_w + n * EMB + kk;
                    float4 f0 = *reinterpret_cast<const float4*>(src);
                    float4 f1 = *reinterpret_cast<const float4*>(src + 4);
                    uint4 t;
                    t.x = f2bf_bits(f0.x) | (f2bf_bits(f0.y) << 16);
                    t.y = f2bf_bits(f0.z) | (f2bf_bits(f0.w) << 16);
                    t.z = f2bf_bits(f1.x) | (f2bf_bits(f1.y) << 16);
                    t.w = f2bf_bits(f1.z) | (f2bf_bits(f1.w) << 16);
                    b = __builtin_bit_cast(bf16x8, t);
                }
                qacc[ntl] = __builtin_amdgcn_mfma_f32_16x16x32_bf16(a, b, qacc[ntl], 0, 0, 0);
            }
        }
        #pragma unroll
        for (int ntl = 0; ntl < 2; ++ntl) {
            int n = (wave * 2 + ntl) * 16 + (lane & 15);
            float bias = Wp_b[n];
            #pragma unroll
            for (int i = 0; i < 4; ++i) {
                int row = ((lane >> 4) << 2) + i;
                if (row < T_BLK) q_lds[row][n] = qacc[ntl][i] + bias;
            }
        }
    }
    __syncthreads();                                   // B2: Abuf free, q_lds visible

    // ---- write chunk 0 (rec) into LDS ----
    #pragma unroll
    for (int it = 0; it < 10; ++it) {
        int idx = tid + it * THREADS;
        int row = idx >> 6, d4 = (idx & 63) << 2;
        unsigned int w0 = f2bf_bits(pf[it].x) | (f2bf_bits(pf[it].y) << 16);
        unsigned int w1 = f2bf_bits(pf[it].z) | (f2bf_bits(pf[it].w) << 16);
        *reinterpret_cast<uint2*>(Abuf + lds_addr(row, d4 * 2)) = make_uint2(w0, w1);
    }
    __syncthreads();                                   // B3: chunk 0 ready

    // ---- T14: issue chunk-1 (edge) loads; drain during chunk-0 compute ----
    #pragma unroll
    for (int it = 0; it < 10; ++it) {
        int idx = tid + it * THREADS;
        int row = idx >> 6, d4 = (idx & 63) << 2;
        pf[it] = *reinterpret_cast<const float4*>(edge + (grow0 + row) * EMB + d4);
    }

    f32x4 acc[5][4] = {};
    kv_compute<USE_FRAG>(0, Abuf, w_frag, Wr_w, Wv_w, lane, wave, acc);
    __syncthreads();                                   // B4: chunk-0 reads done

    #pragma unroll
    for (int it = 0; it < 10; ++it) {
        int idx = tid + it * THREADS;
        int row = idx >> 6, d4 = (idx & 63) << 2;
        unsigned int w0 = f2bf_bits(pf[it].x) | (f2bf_bits(pf[it].y) << 16);
        unsigned int w1 = f2bf_bits(pf[it].z) | (f2bf_bits(pf[it].w) << 16);
        *reinterpret_cast<uint2*>(Abuf + lds_addr(row, d4 * 2)) = make_uint2(w0, w1);
    }
    __syncthreads();                                   // B5: chunk 1 ready

    kv_compute<USE_FRAG>(1, Abuf, w_frag, Wr_w, Wv_w, lane, wave, acc);

    // ---- logit partials (waves 0-3 own K columns); no atomics ----
    if (wave < 4) {
        #pragma unroll
        for (int mt = 0; mt < 5; ++mt) {
            #pragma unroll
            for (int i = 0; i < 4; ++i) {
                int row = mt * 16 + ((lane >> 4) << 2) + i;   // 0..79
                int t = row / NREC;
                float p = 0.f;
                #pragma unroll
                for (int ntl = 0; ntl < 4; ++ntl) {
                    int n = (wave << 6) + (ntl << 4) + (lane & 15);
                    p += acc[mt][ntl][i] * q_lds[t][n];
                }
                p += __shfl_xor(p, 1);
                p += __shfl_xor(p, 2);
                p += __shfl_xor(p, 4);
                p += __shfl_xor(p, 8);
                if ((lane & 15) == 0) logit_part[wave][row] = p;
            }
        }
    }
    __syncthreads();                                   // B6: partials ready

    // ---- softmax over 10 neighbors (Wr_b dropped: shift invariance) ----
    if (tid < T_BLK) {
        float l[NREC], m = -1e30f;
        #pragma unroll
        for (int r = 0; r < NREC; ++r) {
            int row = tid * NREC + r;
            float s = logit_part[0][row] + logit_part[1][row]
                    + logit_part[2][row] + logit_part[3][row];
            l[r] = s * 0.0625f;                        // 1/sqrt(256)
            m = fmaxf(m, l[r]);
        }
        float s = 0.f;
        #pragma unroll
        for (int r = 0; r < NREC; ++r) { l[r] = expf(l[r] - m); s += l[r]; }
        float inv = 1.f / s;
        #pragma unroll
        for (int r = 0; r < NREC; ++r) attnw[tid * NREC + r] = l[r] * inv;
    }
    __syncthreads();                                   // B7: attnw ready

    // ---- PV: waves 4-7 own V columns; atomic-lite (rows pre-reduced per token) ----
    if (wave >= 4) {
        #pragma unroll
        for (int mt = 0; mt < 5; ++mt) {
            int base = mt * 16 + ((lane >> 4) << 2);   // first of 4 consecutive rows
            float w0 = attnw[base + 0], w1 = attnw[base + 1];
            float w2 = attnw[base + 2], w3 = attnw[base + 3];
            int tA = base / NREC, tB = (base + 3) / NREC;
            int nb = (tA + 1) * NREC - base;           // rows belonging to tA (1..4)
            #pragma unroll
            for (int ntl = 0; ntl < 4; ++ntl) {
                int nv = ((wave - 4) << 6) + (ntl << 4) + (lane & 15);
                float v0 = acc[mt][ntl][0] * w0, v1 = acc[mt][ntl][1] * w1;
                float v2 = acc[mt][ntl][2] * w2, v3 = acc[mt][ntl][3] * w3;
                if (tA == tB) {
                    atomicAdd(&out_acc[tA][nv], v0 + v1 + v2 + v3);
                } else {
                    float sA = v0, sB = v3;
                    if (nb == 1)      { sB += v1 + v2; }
                    else if (nb == 2) { sA += v1; sB += v2; }
                    else              { sA += v1 + v2; }
                    atomicAdd(&out_acc[tA][nv], sA);
                    atomicAdd(&out_acc[tB][nv], sB);
                }
            }
        }
    }
    __syncthreads();                                   // B8

    // ---- epilogue: out = q + attn*V + Wv_b (sum(attn)=1 folds the bias) ----
    #pragma unroll
    for (int it = 0; it < 4; ++it) {
        int idx = tid + it * THREADS;
        int t = idx >> 8, o = idx & 255;
        out[(long)(tok0 + t) * OUTD + o] = q_lds[t][o] + out_acc[t][o] + Wv_b[o];
    }
}

extern "C" void kernel_launch(void* const* d_in, const int* in_sizes, int n_in,
                              void* d_out, int out_size, void* d_ws, size_t ws_size,
                              hipStream_t stream) {
    const float* rec  = (const float*)d_in[0];
    const float* pep  = (const float*)d_in[1];
    const float* edge = (const float*)d_in[2];
    const float* Wp_w = (const float*)d_in[3];
    const float* Wp_b = (const float*)d_in[4];
    const float* Wr_w = (const float*)d_in[5];
    // d_in[6] = Wr_b : provably irrelevant (softmax shift invariance)
    const float* Wv_w = (const float*)d_in[7];
    const float* Wv_b = (const float*)d_in[8];
    float* out = (float*)d_out;

    const size_t kv_frag_elems = 32 * 16 * 64 * 8;   // 262144
    const size_t qp_frag_elems = 16 * 8 * 64 * 8;    // 65536
    const size_t need = (kv_frag_elems + qp_frag_elems) * sizeof(short);
    short* w_frag  = (short*)d_ws;
    short* wp_frag = w_frag + kv_frag_elems;

    if (ws_size >= need) {
        prep_wfrag<<<1024, 256, 0, stream>>>(Wp_w, Wr_w, Wv_w, wp_frag, w_frag);
        ga_fused<1><<<N_TOK / T_BLK, THREADS, 0, stream>>>(rec, pep, edge, Wp_w, Wp_b, Wr_w,
                                                           Wv_w, Wv_b, w_frag, wp_frag, out);
    } else {
        ga_fused<0><<<N_TOK / T_BLK, THREADS, 0, stream>>>(rec, pep, edge, Wp_w, Wp_b, Wr_w,
                                                           Wv_w, Wv_b, w_frag, wp_frag, out);
    }
}

// Round 3
// 131.587 us; speedup vs baseline: 3.6839x; 1.9079x over previous
//
#include <hip/hip_runtime.h>
#include <hip/hip_bf16.h>

#define N_TOK   16384   // B * N_PEP
#define NREC    10
#define EMB     256
#define TWO_EMB 512
#define OUTD    256
#define T_BLK   16      // tokens per block
#define THREADS 512     // 8 waves; wave w owns tokens 2w, 2w+1 in streaming phase

typedef __bf16 bf16x8 __attribute__((ext_vector_type(8)));
typedef float  f32x4  __attribute__((ext_vector_type(4)));

static __device__ __forceinline__ unsigned int f2bf_bits(float f) {
    unsigned int u = __builtin_bit_cast(unsigned int, f);
    u = (u + 0x7fffu + ((u >> 16) & 1u)) >> 16;   // RNE bf16
    return u & 0xffffu;
}
static __device__ __forceinline__ unsigned int pack2(float a, float b) {
    return f2bf_bits(a) | (f2bf_bits(b) << 16);
}

// ---------------- weight fragment prep (bf16, MFMA B-fragment order) ----------
// wp_frag: [16 nt][8 kt][64][8]   q GEMM    B[n=o][k=d]   = Wp[n*256+k]
// wr_frag: [32 nt][8 kt][64][8]   qr GEMM   B[n=d][k=o]   = Wr[k*512+n]   (transposed use)
// wv_frag: [16 nt][16 kt][64][8]  out GEMM  B[n=o][k=d]   = Wv[n*512+k]
__global__ void prep_wfrag(const float* __restrict__ Wp,
                           const float* __restrict__ Wr,
                           const float* __restrict__ Wv,
                           short* __restrict__ wp_frag,
                           short* __restrict__ wr_frag,
                           short* __restrict__ wv_frag) {
    int idx = blockIdx.x * blockDim.x + threadIdx.x;   // grid covers 131072
    if (idx < 16 * 8 * 64 * 8) {
        int j = idx & 7, lane = (idx >> 3) & 63, kt = (idx >> 9) & 7, nt = idx >> 12;
        int n = nt * 16 + (lane & 15), k = kt * 32 + ((lane >> 4) << 3) + j;
        wp_frag[idx] = (short)f2bf_bits(Wp[n * EMB + k]);
    }
    if (idx < 32 * 8 * 64 * 8) {
        int j = idx & 7, lane = (idx >> 3) & 63, kt = (idx >> 9) & 7, nt = idx >> 12;
        int n = nt * 16 + (lane & 15), k = kt * 32 + ((lane >> 4) << 3) + j;
        wr_frag[idx] = (short)f2bf_bits(Wr[k * TWO_EMB + n]);
    }
    if (idx < 16 * 16 * 64 * 8) {
        int j = idx & 7, lane = (idx >> 3) & 63, kt = (idx >> 9) & 15, nt = idx >> 13;
        int n = nt * 16 + (lane & 15), k = kt * 32 + ((lane >> 4) << 3) + j;
        wv_frag[idx] = (short)f2bf_bits(Wv[n * TWO_EMB + k]);
    }
}

// B-fragment loaders (frag path or direct-from-f32 fallback)
template<int USE_FRAG>
static __device__ __forceinline__ bf16x8 load_b_rm(const short* __restrict__ frag,
                                                   const float* __restrict__ W,
                                                   int n, int k, int ld) {
    if constexpr (USE_FRAG) {
        return *reinterpret_cast<const bf16x8*>(frag);
    } else {
        const float* s = W + (long)n * ld + k;
        float4 f0 = *reinterpret_cast<const float4*>(s);
        float4 f1 = *reinterpret_cast<const float4*>(s + 4);
        uint4 t = { pack2(f0.x, f0.y), pack2(f0.z, f0.w), pack2(f1.x, f1.y), pack2(f1.z, f1.w) };
        return __builtin_bit_cast(bf16x8, t);
    }
}
template<int USE_FRAG>
static __device__ __forceinline__ bf16x8 load_b_tr(const short* __restrict__ frag,
                                                   const float* __restrict__ W,
                                                   int n, int k, int ld) {
    if constexpr (USE_FRAG) {
        return *reinterpret_cast<const bf16x8*>(frag);
    } else {
        unsigned int p[4];
        #pragma unroll
        for (int jj = 0; jj < 4; ++jj)
            p[jj] = pack2(W[(long)(k + 2 * jj) * ld + n], W[(long)(k + 2 * jj + 1) * ld + n]);
        uint4 t = { p[0], p[1], p[2], p[3] };
        return __builtin_bit_cast(bf16x8, t);
    }
}

// ---------------- fused kernel (commuted-projection formulation) --------------
// per token t:  q  = Wp@pep + bp                      (MFMA, M=16 tile)
//               qr = Wr^T q                           (MFMA; Wr_b drops: softmax shift-inv)
//               logit_r = (qr . x_r)/16, x_r = [rec_r | edge_r]   (streamed, f32, in-reg)
//               attn = softmax(logit); xbar = sum_r attn_r x_r    (in-reg)
//               out = q + Wv@xbar + bv                (MFMA; sum(attn)=1 folds bias)
template<int USE_FRAG>
__launch_bounds__(THREADS, 4)
__global__ void ga2_fused(const float* __restrict__ rec,
                          const float* __restrict__ pep,
                          const float* __restrict__ edge,
                          const float* __restrict__ Wp_w,
                          const float* __restrict__ Wp_b,
                          const float* __restrict__ Wr_w,
                          const float* __restrict__ Wv_w,
                          const float* __restrict__ Wv_b,
                          const short* __restrict__ wp_frag,
                          const short* __restrict__ wr_frag,
                          const short* __restrict__ wv_frag,
                          float* __restrict__ out) {
    // xz: pep bf16 A-tile (rows of 512B) during phase 1a, then xbar bf16 A-tile
    // (rows of 1024B) for phase 3. Both XOR-swizzled.
    __shared__ __align__(16) unsigned char xz[T_BLK * 1024];       // 16 KB
    __shared__ __align__(16) unsigned char qbf[T_BLK * 512];       // 8 KB  (q bf16 A-tile)
    __shared__ float qf[T_BLK][OUTD];                              // 16 KB (q f32, residual)
    __shared__ float qr[T_BLK][TWO_EMB];                           // 32 KB

    const int tid  = threadIdx.x;
    const int lane = tid & 63;
    const int wave = tid >> 6;
    const int tok0 = blockIdx.x * T_BLK;

    // ---- stage pep tile as bf16 (swizzled) ----
    #pragma unroll
    for (int it = 0; it < 2; ++it) {
        int idx = tid + it * THREADS;          // 16 rows x 64 float4
        int row = idx >> 6, d4 = (idx & 63) << 2;
        float4 f = *reinterpret_cast<const float4*>(pep + (long)(tok0 + row) * EMB + d4);
        uint2 w = { pack2(f.x, f.y), pack2(f.z, f.w) };
        *reinterpret_cast<uint2*>(xz + 512 * row + ((d4 * 2 * 2 / 2) ^ ((row & 7) << 4))) = w;
    }
    __syncthreads();                            // B1: pep tile ready

    // ---- 1a: q = pep @ Wp^T + bp   (M=16,K=256,N=256; 2 n-tiles/wave) ----
    {
        f32x4 qacc[2] = {};
        #pragma unroll
        for (int kt = 0; kt < 8; ++kt) {
            int kk = kt * 32 + ((lane >> 4) << 3);
            int row = lane & 15;
            bf16x8 a = *reinterpret_cast<const bf16x8*>(xz + 512 * row + ((kk * 2) ^ ((row & 7) << 4)));
            #pragma unroll
            for (int ntl = 0; ntl < 2; ++ntl) {
                int nt = wave * 2 + ntl;
                bf16x8 b = load_b_rm<USE_FRAG>(wp_frag + ((nt * 8 + kt) * 64 + lane) * 8,
                                               Wp_w, nt * 16 + (lane & 15), kk, EMB);
                qacc[ntl] = __builtin_amdgcn_mfma_f32_16x16x32_bf16(a, b, qacc[ntl], 0, 0, 0);
            }
        }
        #pragma unroll
        for (int ntl = 0; ntl < 2; ++ntl) {
            int n = (wave * 2 + ntl) * 16 + (lane & 15);
            float bias = Wp_b[n];
            #pragma unroll
            for (int i = 0; i < 4; ++i) {
                int row = ((lane >> 4) << 2) + i;
                float v = qacc[ntl][i] + bias;
                qf[row][n] = v;
                *reinterpret_cast<unsigned short*>(qbf + 512 * row + ((n * 2) ^ ((row & 7) << 4)))
                    = (unsigned short)f2bf_bits(v);
            }
        }
    }

    // ---- issue token-A x loads now; they drain under the qr GEMM ----
    const float* srcA = (lane < 32) ? rec : edge;
    const int dloc = (lane * 8) & 255;
    float4 px0[NREC], px1[NREC];
    {
        const float* base = srcA + ((long)(tok0 + wave * 2) * NREC) * EMB + dloc;
        #pragma unroll
        for (int r = 0; r < NREC; ++r) {
            px0[r] = *reinterpret_cast<const float4*>(base + r * EMB);
            px1[r] = *reinterpret_cast<const float4*>(base + r * EMB + 4);
        }
    }
    __syncthreads();                            // B2: qbf ready

    // ---- 1b: qr = q @ Wr   (M=16,K=256,N=512; 4 n-tiles/wave) ----
    {
        f32x4 racc[4] = {};
        #pragma unroll
        for (int kt = 0; kt < 8; ++kt) {
            int kk = kt * 32 + ((lane >> 4) << 3);
            int row = lane & 15;
            bf16x8 a = *reinterpret_cast<const bf16x8*>(qbf + 512 * row + ((kk * 2) ^ ((row & 7) << 4)));
            #pragma unroll
            for (int ntl = 0; ntl < 4; ++ntl) {
                int nt = wave * 4 + ntl;
                bf16x8 b = load_b_tr<USE_FRAG>(wr_frag + ((nt * 8 + kt) * 64 + lane) * 8,
                                               Wr_w, nt * 16 + (lane & 15), kk, TWO_EMB);
                racc[ntl] = __builtin_amdgcn_mfma_f32_16x16x32_bf16(a, b, racc[ntl], 0, 0, 0);
            }
        }
        #pragma unroll
        for (int ntl = 0; ntl < 4; ++ntl) {
            int n = (wave * 4 + ntl) * 16 + (lane & 15);
            #pragma unroll
            for (int i = 0; i < 4; ++i)
                qr[((lane >> 4) << 2) + i][n] = racc[ntl][i];
        }
    }
    __syncthreads();                            // B3: qr ready

    // ---- streaming: logits -> softmax -> xbar, all in registers ----
    #pragma unroll
    for (int tk = 0; tk < 2; ++tk) {
        const int t = wave * 2 + tk;
        float4 qa = *reinterpret_cast<const float4*>(&qr[t][lane * 8]);
        float4 qb = *reinterpret_cast<const float4*>(&qr[t][lane * 8 + 4]);
        float l[NREC];
        #pragma unroll
        for (int r = 0; r < NREC; ++r) {
            float p = qa.x * px0[r].x + qa.y * px0[r].y + qa.z * px0[r].z + qa.w * px0[r].w
                    + qb.x * px1[r].x + qb.y * px1[r].y + qb.z * px1[r].z + qb.w * px1[r].w;
            p += __shfl_xor(p, 1);
            p += __shfl_xor(p, 2);
            p += __shfl_xor(p, 4);
            p += __shfl_xor(p, 8);
            p += __shfl_xor(p, 16);
            p += __shfl_xor(p, 32);
            l[r] = p * 0.0625f;                 // 1/sqrt(256)
        }
        float m = l[0];
        #pragma unroll
        for (int r = 1; r < NREC; ++r) m = fmaxf(m, l[r]);
        float s = 0.f;
        #pragma unroll
        for (int r = 0; r < NREC; ++r) { l[r] = __expf(l[r] - m); s += l[r]; }
        float inv = 1.f / s;
        float4 xb0 = make_float4(0.f, 0.f, 0.f, 0.f), xb1 = xb0;
        #pragma unroll
        for (int r = 0; r < NREC; ++r) {
            float w = l[r] * inv;
            xb0.x += w * px0[r].x; xb0.y += w * px0[r].y; xb0.z += w * px0[r].z; xb0.w += w * px0[r].w;
            xb1.x += w * px1[r].x; xb1.y += w * px1[r].y; xb1.z += w * px1[r].z; xb1.w += w * px1[r].w;
        }
        // prefetch token B's x (WAR on px limits overlap; acceptable)
        if (tk == 0) {
            const float* base = srcA + ((long)(tok0 + wave * 2 + 1) * NREC) * EMB + dloc;
            #pragma unroll
            for (int r = 0; r < NREC; ++r) {
                px0[r] = *reinterpret_cast<const float4*>(base + r * EMB);
                px1[r] = *reinterpret_cast<const float4*>(base + r * EMB + 4);
            }
        }
        uint4 wv4 = { pack2(xb0.x, xb0.y), pack2(xb0.z, xb0.w),
                      pack2(xb1.x, xb1.y), pack2(xb1.z, xb1.w) };
        *reinterpret_cast<uint4*>(xz + 1024 * t + ((lane * 16) ^ ((t & 7) << 4))) = wv4;
    }
    __syncthreads();                            // B4: xbar tile ready

    // ---- ph3: out = q + Wv @ xbar + bv  (M=16,K=512,N=256; 2 n-tiles/wave) ----
    {
        f32x4 oacc[2] = {};
        #pragma unroll
        for (int kt = 0; kt < 16; ++kt) {
            int kk = kt * 32 + ((lane >> 4) << 3);
            int row = lane & 15;
            bf16x8 a = *reinterpret_cast<const bf16x8*>(xz + 1024 * row + ((kk * 2) ^ ((row & 7) << 4)));
            #pragma unroll
            for (int ntl = 0; ntl < 2; ++ntl) {
                int nt = wave * 2 + ntl;
                bf16x8 b = load_b_rm<USE_FRAG>(wv_frag + ((nt * 16 + kt) * 64 + lane) * 8,
                                               Wv_w, nt * 16 + (lane & 15), kk, TWO_EMB);
                oacc[ntl] = __builtin_amdgcn_mfma_f32_16x16x32_bf16(a, b, oacc[ntl], 0, 0, 0);
            }
        }
        #pragma unroll
        for (int ntl = 0; ntl < 2; ++ntl) {
            int n = (wave * 2 + ntl) * 16 + (lane & 15);
            float bv = Wv_b[n];
            #pragma unroll
            for (int i = 0; i < 4; ++i) {
                int row = ((lane >> 4) << 2) + i;
                out[(long)(tok0 + row) * OUTD + n] = qf[row][n] + oacc[ntl][i] + bv;
            }
        }
    }
}

extern "C" void kernel_launch(void* const* d_in, const int* in_sizes, int n_in,
                              void* d_out, int out_size, void* d_ws, size_t ws_size,
                              hipStream_t stream) {
    const float* rec  = (const float*)d_in[0];
    const float* pep  = (const float*)d_in[1];
    const float* edge = (const float*)d_in[2];
    const float* Wp_w = (const float*)d_in[3];
    const float* Wp_b = (const float*)d_in[4];
    const float* Wr_w = (const float*)d_in[5];
    // d_in[6] = Wr_b : irrelevant (softmax shift invariance)
    const float* Wv_w = (const float*)d_in[7];
    const float* Wv_b = (const float*)d_in[8];
    float* out = (float*)d_out;

    const size_t wp_elems = 16 * 8 * 64 * 8;    // 65536
    const size_t wr_elems = 32 * 8 * 64 * 8;    // 131072
    const size_t wv_elems = 16 * 16 * 64 * 8;   // 131072
    const size_t need = (wp_elems + wr_elems + wv_elems) * sizeof(short);
    short* wp_frag = (short*)d_ws;
    short* wr_frag = wp_frag + wp_elems;
    short* wv_frag = wr_frag + wr_elems;

    if (ws_size >= need) {
        prep_wfrag<<<512, 256, 0, stream>>>(Wp_w, Wr_w, Wv_w, wp_frag, wr_frag, wv_frag);
        ga2_fused<1><<<N_TOK / T_BLK, THREADS, 0, stream>>>(rec, pep, edge, Wp_w, Wp_b, Wr_w,
                                                            Wv_w, Wv_b, wp_frag, wr_frag, wv_frag, out);
    } else {
        ga2_fused<0><<<N_TOK / T_BLK, THREADS, 0, stream>>>(rec, pep, edge, Wp_w, Wp_b, Wr_w,
                                                            Wv_w, Wv_b, wp_frag, wr_frag, wv_frag, out);
    }
}